// Round 1
// baseline (57.285 us; speedup 1.0000x reference)
//
#include <hip/hip_runtime.h>

constexpr int H  = 8;
constexpr int T  = 2048;
constexpr int DH = 64;
constexpr int D  = 64;

__global__ __launch_bounds__(256) void wayfinder_attn_kernel(
    const float* __restrict__ q,
    const float* __restrict__ k,
    const float* __restrict__ v,
    const float* __restrict__ eb,     // edge_type_bias, 4 floats
    const int*   __restrict__ nidx,   // (H,T,D)
    const int*   __restrict__ etyp,   // (H,T,D)
    float* __restrict__ out)          // (1,H,T,DH)
{
    const int wave = threadIdx.x >> 6;          // 0..3
    const int lane = threadIdx.x & 63;          // 0..63
    const int flat = (blockIdx.x << 2) + wave;  // h*T + t
    const int h    = flat >> 11;                // / T
    const int t    = flat & (T - 1);

    __shared__ float  sq[4][64];
    __shared__ float2 sw[4][64];   // {weight, bitcast(s_idx)}

    const long long rowoff = (long long)flat * DH;

    // stage q row into LDS (coalesced: lane c loads channel c)
    sq[wave][lane] = q[rowoff + lane];

    // per-lane neighbor metadata (coalesced)
    const long long noff = (long long)flat * D + lane;
    const int  idx = nidx[noff];
    const int  et  = etyp[noff];
    const int  s   = min(max(idx, 0), T - 1);
    const bool msk = (idx >= 0) && (idx <= t);

    const float4 ebv  = *reinterpret_cast<const float4*>(eb);
    const float  bias = (et == 1) ? ebv.x : (et == 2) ? ebv.y :
                        (et == 3) ? ebv.z : (et == 4) ? ebv.w : 0.0f;

    __syncthreads();

    // ---- QK^T: lane n computes dot(q[t], k[s_n]) ----
    float acc = 0.0f;
    {
        const float* krow = k + (long long)(h * T + s) * DH;
        #pragma unroll
        for (int c = 0; c < DH; c += 4) {
            const float4 kv = *reinterpret_cast<const float4*>(krow + c);
            const float4 qv = *reinterpret_cast<const float4*>(&sq[wave][c]);
            acc += qv.x * kv.x;
            acc += qv.y * kv.y;
            acc += qv.z * kv.z;
            acc += qv.w * kv.w;
        }
    }
    const float masked = msk ? (acc * 0.125f + bias) : -1e30f;

    // ---- masked softmax over 64 lanes ----
    float mx = masked;
    #pragma unroll
    for (int off = 32; off > 0; off >>= 1)
        mx = fmaxf(mx, __shfl_xor(mx, off));

    const float e = msk ? __expf(masked - mx) : 0.0f;

    float sum = e;
    #pragma unroll
    for (int off = 32; off > 0; off >>= 1)
        sum += __shfl_xor(sum, off);

    const float w = e / fmaxf(sum, 1e-9f);

    sw[wave][lane] = make_float2(w, __int_as_float(s));

    __syncthreads();

    // ---- PV: lane = output channel c; each n-iter is a coalesced v-row read ----
    float y = 0.0f;
    const float* vhead = v + (long long)h * T * DH;
    #pragma unroll 8
    for (int n = 0; n < D; ++n) {
        const float2 ws = sw[wave][n];
        const int    sn = __float_as_int(ws.y);
        y += ws.x * vhead[sn * DH + lane];
    }
    out[rowoff + lane] = y;
}

extern "C" void kernel_launch(void* const* d_in, const int* in_sizes, int n_in,
                              void* d_out, int out_size, void* d_ws, size_t ws_size,
                              hipStream_t stream) {
    const float* q    = (const float*)d_in[0];
    const float* k    = (const float*)d_in[1];
    const float* v    = (const float*)d_in[2];
    const float* eb   = (const float*)d_in[3];
    const int*   nidx = (const int*)d_in[4];
    const int*   etyp = (const int*)d_in[5];
    float* out = (float*)d_out;

    dim3 grid(H * T / 4);
    dim3 block(256);
    hipLaunchKernelGGL(wayfinder_attn_kernel, grid, block, 0, stream,
                       q, k, v, eb, nidx, etyp, out);
}

// Round 2
// 38.572 us; speedup vs baseline: 1.4851x; 1.4851x over previous
//
#include <hip/hip_runtime.h>

constexpr int H  = 8;
constexpr int T  = 2048;
constexpr int DH = 64;
constexpr int D  = 64;

__global__ __launch_bounds__(256) void wayfinder_attn_kernel(
    const float* __restrict__ q,
    const float* __restrict__ k,
    const float* __restrict__ v,
    const float* __restrict__ eb,     // edge_type_bias, 4 floats
    const int*   __restrict__ nidx,   // (H,T,D)
    const int*   __restrict__ etyp,   // (H,T,D)
    float* __restrict__ out)          // (1,H,T,DH)
{
    const int wave = threadIdx.x >> 6;          // 0..3
    const int lane = threadIdx.x & 63;          // 0..63
    const int flat = (blockIdx.x << 2) + wave;  // h*T + t
    const int h    = flat >> 11;                // / T
    const int t    = flat & (T - 1);

    const int grp = lane >> 4;                  // 0..3   (row within a 4-row pack)
    const int sub = lane & 15;                  // 0..15  (float4 slice of the row)

    __shared__ int    sidx[4][64];              // clamped gather index per n
    __shared__ float  ssc [4][64];              // raw dot score per n
    __shared__ float2 swv [4][64];              // {weight, bitcast(s_idx)} per n

    const long long rowoff = (long long)flat * DH;

    // ---- metadata phase: lane = neighbor n (coalesced) ----
    const long long noff = (long long)flat * D + lane;
    const int  idx = nidx[noff];
    const int  et  = etyp[noff];
    const int  s   = min(max(idx, 0), T - 1);
    const bool msk = (idx >= 0) && (idx <= t);

    const float4 ebv  = *reinterpret_cast<const float4*>(eb);
    const float  bias = (et == 1) ? ebv.x : (et == 2) ? ebv.y :
                        (et == 3) ? ebv.z : (et == 4) ? ebv.w : 0.0f;
    sidx[wave][lane] = s;

    // q fragment: channels sub*4 .. sub*4+3 (broadcast load, 4 lines/wave)
    const float4 qf = *reinterpret_cast<const float4*>(q + rowoff + sub * 4);

    __syncthreads();

    // ---- QK^T: 16 lanes cooperate per k-row, 4 rows per instruction ----
    const float* khead = k + (long long)h * T * DH;
    #pragma unroll
    for (int i = 0; i < 16; ++i) {
        const int n  = i * 4 + grp;
        const int sn = sidx[wave][n];
        const float4 kf = *reinterpret_cast<const float4*>(khead + sn * DH + sub * 4);
        float p = qf.x * kf.x + qf.y * kf.y + qf.z * kf.z + qf.w * kf.w;
        p += __shfl_xor(p, 1);
        p += __shfl_xor(p, 2);
        p += __shfl_xor(p, 4);
        p += __shfl_xor(p, 8);
        if (sub == 0) ssc[wave][n] = p;
    }

    __syncthreads();

    // ---- masked softmax over 64 neighbors (lane = n) ----
    const float sc     = ssc[wave][lane];
    const float masked = msk ? (sc * 0.125f + bias) : -1e30f;

    float mx = masked;
    #pragma unroll
    for (int off = 32; off > 0; off >>= 1)
        mx = fmaxf(mx, __shfl_xor(mx, off));

    const float e = msk ? __expf(masked - mx) : 0.0f;

    float sum = e;
    #pragma unroll
    for (int off = 32; off > 0; off >>= 1)
        sum += __shfl_xor(sum, off);

    const float w = e / fmaxf(sum, 1e-9f);
    swv[wave][lane] = make_float2(w, __int_as_float(s));

    __syncthreads();

    // ---- PV: 16 lanes cooperate per v-row, 4 rows per instruction ----
    const float* vhead = v + (long long)h * T * DH;
    float4 acc = make_float4(0.f, 0.f, 0.f, 0.f);
    #pragma unroll
    for (int i = 0; i < 16; ++i) {
        const int    n  = i * 4 + grp;
        const float2 ws = swv[wave][n];
        const int    sn = __float_as_int(ws.y);
        const float4 vf = *reinterpret_cast<const float4*>(vhead + sn * DH + sub * 4);
        acc.x += ws.x * vf.x;
        acc.y += ws.x * vf.y;
        acc.z += ws.x * vf.z;
        acc.w += ws.x * vf.w;
    }
    // sum partials across the 4 row-groups (lanes sharing `sub`)
    #pragma unroll
    for (int off = 16; off <= 32; off <<= 1) {
        acc.x += __shfl_xor(acc.x, off);
        acc.y += __shfl_xor(acc.y, off);
        acc.z += __shfl_xor(acc.z, off);
        acc.w += __shfl_xor(acc.w, off);
    }
    if (lane < 16)
        *reinterpret_cast<float4*>(out + rowoff + sub * 4) = acc;
}

extern "C" void kernel_launch(void* const* d_in, const int* in_sizes, int n_in,
                              void* d_out, int out_size, void* d_ws, size_t ws_size,
                              hipStream_t stream) {
    const float* q    = (const float*)d_in[0];
    const float* k    = (const float*)d_in[1];
    const float* v    = (const float*)d_in[2];
    const float* eb   = (const float*)d_in[3];
    const int*   nidx = (const int*)d_in[4];
    const int*   etyp = (const int*)d_in[5];
    float* out = (float*)d_out;

    dim3 grid(H * T / 4);
    dim3 block(256);
    hipLaunchKernelGGL(wayfinder_attn_kernel, grid, block, 0, stream,
                       q, k, v, eb, nidx, etyp, out);
}

// Round 3
// 31.994 us; speedup vs baseline: 1.7905x; 1.2056x over previous
//
#include <hip/hip_runtime.h>
#include <hip/hip_fp16.h>

constexpr int H  = 8;
constexpr int T  = 2048;
constexpr int DH = 64;
constexpr int D  = 64;
constexpr int NKV = H * T * DH;   // 1M elements per tensor

// ---- prepass: f32 -> f16 for k and v (into workspace) ----
__global__ __launch_bounds__(256) void cvt_f32_f16(
    const float* __restrict__ k, const float* __restrict__ v,
    __half* __restrict__ kh, __half* __restrict__ vh)
{
    const int i = (blockIdx.x * 256 + threadIdx.x) * 8;
    const float* src = (blockIdx.y == 0) ? k : v;
    __half*      dst = (blockIdx.y == 0) ? kh : vh;
    const float4 a = *reinterpret_cast<const float4*>(src + i);
    const float4 b = *reinterpret_cast<const float4*>(src + i + 4);
    __half2 hh[4];
    hh[0] = __float22half2_rn(make_float2(a.x, a.y));
    hh[1] = __float22half2_rn(make_float2(a.z, a.w));
    hh[2] = __float22half2_rn(make_float2(b.x, b.y));
    hh[3] = __float22half2_rn(make_float2(b.z, b.w));
    *reinterpret_cast<float4*>(dst + i) = *reinterpret_cast<const float4*>(hh);
}

// ---- main kernel: fp16 gathered k/v, 8 lanes per row, early-V ----
__global__ __launch_bounds__(256) void wayfinder_attn_f16(
    const float* __restrict__ q,
    const __half* __restrict__ kh,
    const __half* __restrict__ vh,
    const float* __restrict__ eb,
    const int*   __restrict__ nidx,
    const int*   __restrict__ etyp,
    float* __restrict__ out)
{
    const int wave = threadIdx.x >> 6;
    const int lane = threadIdx.x & 63;
    const int flat = (blockIdx.x << 2) + wave;   // h*T + t
    const int h    = flat >> 11;
    const int t    = flat & (T - 1);
    const int grp  = lane >> 3;                  // 0..7: row within 8-row pack
    const int sub  = lane & 7;                   // 0..7: 8-channel slice

    __shared__ int   sidx[4][64];
    __shared__ float ssc [4][64];
    __shared__ float swt [4][64];

    const long long rowoff = (long long)flat * DH;

    // metadata: lane = neighbor n (coalesced)
    const long long noff = (long long)flat * D + lane;
    const int  idx = nidx[noff];
    const int  et  = etyp[noff];
    const int  s   = min(max(idx, 0), T - 1);
    const bool msk = (idx >= 0) && (idx <= t);
    const float4 ebv  = *reinterpret_cast<const float4*>(eb);
    const float  bias = (et == 1) ? ebv.x : (et == 2) ? ebv.y :
                        (et == 3) ? ebv.z : (et == 4) ? ebv.w : 0.0f;
    sidx[wave][lane] = s;

    // q fragment: channels sub*8 .. sub*8+7 (broadcast across grp)
    const float4 q0 = *reinterpret_cast<const float4*>(q + rowoff + sub * 8);
    const float4 q1 = *reinterpret_cast<const float4*>(q + rowoff + sub * 8 + 4);

    __syncthreads();

    const __half* khead = kh + (long long)h * T * DH;
    const __half* vhead = vh + (long long)h * T * DH;

    int sn[8];
    #pragma unroll
    for (int i = 0; i < 8; ++i) sn[i] = sidx[wave][i * 8 + grp];

    // K gathers: one dwordx4 = one full fp16 row per 8-lane group
    float4 kf[8];
    #pragma unroll
    for (int i = 0; i < 8; ++i)
        kf[i] = *reinterpret_cast<const float4*>(khead + (long long)sn[i] * DH + sub * 8);

    // V gathers issued EARLY (latency hidden under QK-reduce + softmax)
    float4 vf[8];
    #pragma unroll
    for (int i = 0; i < 8; ++i)
        vf[i] = *reinterpret_cast<const float4*>(vhead + (long long)sn[i] * DH + sub * 8);

    // QK: per-lane 8-channel partial, reduce across sub (3 shfl levels)
    #pragma unroll
    for (int i = 0; i < 8; ++i) {
        const __half2* kp = reinterpret_cast<const __half2*>(&kf[i]);
        const float2 f0 = __half22float2(kp[0]);
        const float2 f1 = __half22float2(kp[1]);
        const float2 f2 = __half22float2(kp[2]);
        const float2 f3 = __half22float2(kp[3]);
        float p = q0.x * f0.x + q0.y * f0.y + q0.z * f1.x + q0.w * f1.y
                + q1.x * f2.x + q1.y * f2.y + q1.z * f3.x + q1.w * f3.y;
        p += __shfl_xor(p, 1);
        p += __shfl_xor(p, 2);
        p += __shfl_xor(p, 4);
        if (sub == 0) ssc[wave][i * 8 + grp] = p;
    }

    __syncthreads();

    // masked softmax over 64 neighbors (lane = n)
    const float sc     = ssc[wave][lane];
    const float masked = msk ? (sc * 0.125f + bias) : -1e30f;
    float mx = masked;
    #pragma unroll
    for (int off = 32; off > 0; off >>= 1)
        mx = fmaxf(mx, __shfl_xor(mx, off));
    const float e = msk ? __expf(masked - mx) : 0.0f;
    float sum = e;
    #pragma unroll
    for (int off = 32; off > 0; off >>= 1)
        sum += __shfl_xor(sum, off);
    swt[wave][lane] = e / fmaxf(sum, 1e-9f);

    __syncthreads();

    // PV from registers
    float acc[8] = {0.f, 0.f, 0.f, 0.f, 0.f, 0.f, 0.f, 0.f};
    #pragma unroll
    for (int i = 0; i < 8; ++i) {
        const float w = swt[wave][i * 8 + grp];
        const __half2* vp = reinterpret_cast<const __half2*>(&vf[i]);
        const float2 f0 = __half22float2(vp[0]);
        const float2 f1 = __half22float2(vp[1]);
        const float2 f2 = __half22float2(vp[2]);
        const float2 f3 = __half22float2(vp[3]);
        acc[0] += w * f0.x;  acc[1] += w * f0.y;
        acc[2] += w * f1.x;  acc[3] += w * f1.y;
        acc[4] += w * f2.x;  acc[5] += w * f2.y;
        acc[6] += w * f3.x;  acc[7] += w * f3.y;
    }
    // reduce across the 8 row-groups
    #pragma unroll
    for (int c = 0; c < 8; ++c) {
        acc[c] += __shfl_xor(acc[c], 8);
        acc[c] += __shfl_xor(acc[c], 16);
        acc[c] += __shfl_xor(acc[c], 32);
    }
    if (lane < 8) {
        *reinterpret_cast<float4*>(out + rowoff + lane * 8) =
            make_float4(acc[0], acc[1], acc[2], acc[3]);
        *reinterpret_cast<float4*>(out + rowoff + lane * 8 + 4) =
            make_float4(acc[4], acc[5], acc[6], acc[7]);
    }
}

// ---- fallback: round-2 f32 kernel (used if ws too small) ----
__global__ __launch_bounds__(256) void wayfinder_attn_f32(
    const float* __restrict__ q, const float* __restrict__ k,
    const float* __restrict__ v, const float* __restrict__ eb,
    const int* __restrict__ nidx, const int* __restrict__ etyp,
    float* __restrict__ out)
{
    const int wave = threadIdx.x >> 6;
    const int lane = threadIdx.x & 63;
    const int flat = (blockIdx.x << 2) + wave;
    const int h    = flat >> 11;
    const int t    = flat & (T - 1);
    const int grp  = lane >> 4;
    const int sub  = lane & 15;

    __shared__ int    sidx[4][64];
    __shared__ float  ssc [4][64];
    __shared__ float2 swv [4][64];

    const long long rowoff = (long long)flat * DH;
    const long long noff = (long long)flat * D + lane;
    const int  idx = nidx[noff];
    const int  et  = etyp[noff];
    const int  s   = min(max(idx, 0), T - 1);
    const bool msk = (idx >= 0) && (idx <= t);
    const float4 ebv  = *reinterpret_cast<const float4*>(eb);
    const float  bias = (et == 1) ? ebv.x : (et == 2) ? ebv.y :
                        (et == 3) ? ebv.z : (et == 4) ? ebv.w : 0.0f;
    sidx[wave][lane] = s;
    const float4 qf = *reinterpret_cast<const float4*>(q + rowoff + sub * 4);
    __syncthreads();

    const float* khead = k + (long long)h * T * DH;
    #pragma unroll
    for (int i = 0; i < 16; ++i) {
        const int n  = i * 4 + grp;
        const int sn = sidx[wave][n];
        const float4 kf = *reinterpret_cast<const float4*>(khead + sn * DH + sub * 4);
        float p = qf.x * kf.x + qf.y * kf.y + qf.z * kf.z + qf.w * kf.w;
        p += __shfl_xor(p, 1);
        p += __shfl_xor(p, 2);
        p += __shfl_xor(p, 4);
        p += __shfl_xor(p, 8);
        if (sub == 0) ssc[wave][n] = p;
    }
    __syncthreads();

    const float sc     = ssc[wave][lane];
    const float masked = msk ? (sc * 0.125f + bias) : -1e30f;
    float mx = masked;
    #pragma unroll
    for (int off = 32; off > 0; off >>= 1) mx = fmaxf(mx, __shfl_xor(mx, off));
    const float e = msk ? __expf(masked - mx) : 0.0f;
    float sum = e;
    #pragma unroll
    for (int off = 32; off > 0; off >>= 1) sum += __shfl_xor(sum, off);
    const float w = e / fmaxf(sum, 1e-9f);
    swv[wave][lane] = make_float2(w, __int_as_float(s));
    __syncthreads();

    const float* vhead = v + (long long)h * T * DH;
    float4 acc = make_float4(0.f, 0.f, 0.f, 0.f);
    #pragma unroll
    for (int i = 0; i < 16; ++i) {
        const int    n  = i * 4 + grp;
        const float2 ws = swv[wave][n];
        const int    sn = __float_as_int(ws.y);
        const float4 vf = *reinterpret_cast<const float4*>(vhead + sn * DH + sub * 4);
        acc.x += ws.x * vf.x; acc.y += ws.x * vf.y;
        acc.z += ws.x * vf.z; acc.w += ws.x * vf.w;
    }
    #pragma unroll
    for (int off = 16; off <= 32; off <<= 1) {
        acc.x += __shfl_xor(acc.x, off); acc.y += __shfl_xor(acc.y, off);
        acc.z += __shfl_xor(acc.z, off); acc.w += __shfl_xor(acc.w, off);
    }
    if (lane < 16)
        *reinterpret_cast<float4*>(out + rowoff + sub * 4) = acc;
}

extern "C" void kernel_launch(void* const* d_in, const int* in_sizes, int n_in,
                              void* d_out, int out_size, void* d_ws, size_t ws_size,
                              hipStream_t stream) {
    const float* q    = (const float*)d_in[0];
    const float* k    = (const float*)d_in[1];
    const float* v    = (const float*)d_in[2];
    const float* eb   = (const float*)d_in[3];
    const int*   nidx = (const int*)d_in[4];
    const int*   etyp = (const int*)d_in[5];
    float* out = (float*)d_out;

    const size_t need = (size_t)2 * NKV * sizeof(__half);   // 4 MB
    if (ws_size >= need) {
        __half* kh = (__half*)d_ws;
        __half* vh = kh + NKV;
        dim3 cgrid(NKV / (256 * 8), 2);
        hipLaunchKernelGGL(cvt_f32_f16, cgrid, dim3(256), 0, stream, k, v, kh, vh);
        hipLaunchKernelGGL(wayfinder_attn_f16, dim3(H * T / 4), dim3(256), 0, stream,
                           q, kh, vh, eb, nidx, etyp, out);
    } else {
        hipLaunchKernelGGL(wayfinder_attn_f32, dim3(H * T / 4), dim3(256), 0, stream,
                           q, k, v, eb, nidx, etyp, out);
    }
}

// Round 4
// 28.269 us; speedup vs baseline: 2.0264x; 1.1318x over previous
//
#include <hip/hip_runtime.h>
#include <hip/hip_fp16.h>

constexpr int H  = 8;
constexpr int T  = 2048;
constexpr int DH = 64;
constexpr int D  = 64;
constexpr int NKV = H * T * DH;   // 1M elements per tensor

// ---- prepass: f32 -> f16 for k and v (into workspace) ----
__global__ __launch_bounds__(256) void cvt_f32_f16(
    const float* __restrict__ k, const float* __restrict__ v,
    __half* __restrict__ kh, __half* __restrict__ vh)
{
    const int i = (blockIdx.x * 256 + threadIdx.x) * 8;
    const float* src = (blockIdx.y == 0) ? k : v;
    __half*      dst = (blockIdx.y == 0) ? kh : vh;
    const float4 a = *reinterpret_cast<const float4*>(src + i);
    const float4 b = *reinterpret_cast<const float4*>(src + i + 4);
    __half2 hh[4];
    hh[0] = __float22half2_rn(make_float2(a.x, a.y));
    hh[1] = __float22half2_rn(make_float2(a.z, a.w));
    hh[2] = __float22half2_rn(make_float2(b.x, b.y));
    hh[3] = __float22half2_rn(make_float2(b.z, b.w));
    *reinterpret_cast<float4*>(dst + i) = *reinterpret_cast<const float4*>(hh);
}

// ---- main: fp16 gathers, no LDS, no barriers; all cross-lane via shfl ----
// Layout: grp = lane>>3 (one of 8 row-groups), sub = lane&7 (8-ch slice).
// Register entry i <-> neighbor n = i*8 + grp. After the intra-group QK
// reduce, every lane of a group holds its group's 8 full scores, so softmax
// is local-over-8 + 3 cross-group shfl levels, and weights are already in
// the layout PV consumes.
__global__ __launch_bounds__(256) void wayfinder_attn_f16(
    const float* __restrict__ q,
    const __half* __restrict__ kh,
    const __half* __restrict__ vh,
    const float* __restrict__ eb,
    const int*   __restrict__ nidx,
    const int*   __restrict__ etyp,
    float* __restrict__ out)
{
    const int wave = threadIdx.x >> 6;
    const int lane = threadIdx.x & 63;
    const int flat = (blockIdx.x << 2) + wave;   // h*T + t
    const int h    = flat >> 11;
    const int t    = flat & (T - 1);
    const int grp  = lane >> 3;
    const int sub  = lane & 7;

    const long long rowoff = (long long)flat * DH;
    const long long noff   = (long long)flat * D + lane;

    // coalesced metadata load at lane = n
    const int idx_n = nidx[noff];
    const int et_n  = etyp[noff];
    const float4 ebv = *reinterpret_cast<const float4*>(eb);
    const float bias_n = (et_n == 1) ? ebv.x : (et_n == 2) ? ebv.y :
                         (et_n == 3) ? ebv.z : (et_n == 4) ? ebv.w : 0.0f;

    // redistribute to PV layout: entry i holds data for neighbor i*8+grp
    int   idx_i[8];
    float bias_i[8];
    #pragma unroll
    for (int i = 0; i < 8; ++i) {
        idx_i[i]  = __shfl(idx_n,  i * 8 + grp);
        bias_i[i] = __shfl(bias_n, i * 8 + grp);
    }

    const __half* khead = kh + (long long)h * T * DH;
    const __half* vhead = vh + (long long)h * T * DH;

    // gathers: one dwordx4 = full fp16 row per 8-lane group; K and V both
    // issued up front (16 independent loads in flight)
    float4 kf[8], vf[8];
    #pragma unroll
    for (int i = 0; i < 8; ++i) {
        const int s = min(max(idx_i[i], 0), T - 1);
        const long long ro = (long long)s * DH + sub * 8;
        kf[i] = *reinterpret_cast<const float4*>(khead + ro);
        vf[i] = *reinterpret_cast<const float4*>(vhead + ro);
    }

    // q fragment: channels sub*8 .. sub*8+7 (broadcast across grp)
    const float4 q0 = *reinterpret_cast<const float4*>(q + rowoff + sub * 8);
    const float4 q1 = *reinterpret_cast<const float4*>(q + rowoff + sub * 8 + 4);

    // QK: per-lane 8-channel partial, full dot via 3 intra-group shfl levels
    float sc[8];
    #pragma unroll
    for (int i = 0; i < 8; ++i) {
        const __half2* kp = reinterpret_cast<const __half2*>(&kf[i]);
        const float2 f0 = __half22float2(kp[0]);
        const float2 f1 = __half22float2(kp[1]);
        const float2 f2 = __half22float2(kp[2]);
        const float2 f3 = __half22float2(kp[3]);
        float p = q0.x * f0.x + q0.y * f0.y + q0.z * f1.x + q0.w * f1.y
                + q1.x * f2.x + q1.y * f2.y + q1.z * f3.x + q1.w * f3.y;
        p += __shfl_xor(p, 1);
        p += __shfl_xor(p, 2);
        p += __shfl_xor(p, 4);
        sc[i] = p;
    }

    // masked softmax: local over 8, then 3 cross-group levels
    bool  msk[8];
    float masked[8];
    float mx = -1e30f;
    #pragma unroll
    for (int i = 0; i < 8; ++i) {
        msk[i]    = (idx_i[i] >= 0) && (idx_i[i] <= t);
        masked[i] = msk[i] ? (sc[i] * 0.125f + bias_i[i]) : -1e30f;
        mx = fmaxf(mx, masked[i]);
    }
    mx = fmaxf(mx, __shfl_xor(mx, 8));
    mx = fmaxf(mx, __shfl_xor(mx, 16));
    mx = fmaxf(mx, __shfl_xor(mx, 32));

    float e[8];
    float sum = 0.0f;
    #pragma unroll
    for (int i = 0; i < 8; ++i) {
        e[i] = msk[i] ? __expf(masked[i] - mx) : 0.0f;
        sum += e[i];
    }
    sum += __shfl_xor(sum, 8);
    sum += __shfl_xor(sum, 16);
    sum += __shfl_xor(sum, 32);
    const float rden = 1.0f / fmaxf(sum, 1e-9f);

    // PV from registers (weights already in this layout)
    float acc[8] = {0.f, 0.f, 0.f, 0.f, 0.f, 0.f, 0.f, 0.f};
    #pragma unroll
    for (int i = 0; i < 8; ++i) {
        const float w = e[i] * rden;
        const __half2* vp = reinterpret_cast<const __half2*>(&vf[i]);
        const float2 f0 = __half22float2(vp[0]);
        const float2 f1 = __half22float2(vp[1]);
        const float2 f2 = __half22float2(vp[2]);
        const float2 f3 = __half22float2(vp[3]);
        acc[0] += w * f0.x;  acc[1] += w * f0.y;
        acc[2] += w * f1.x;  acc[3] += w * f1.y;
        acc[4] += w * f2.x;  acc[5] += w * f2.y;
        acc[6] += w * f3.x;  acc[7] += w * f3.y;
    }
    #pragma unroll
    for (int c = 0; c < 8; ++c) {
        acc[c] += __shfl_xor(acc[c], 8);
        acc[c] += __shfl_xor(acc[c], 16);
        acc[c] += __shfl_xor(acc[c], 32);
    }
    if (lane < 8) {
        *reinterpret_cast<float4*>(out + rowoff + lane * 8) =
            make_float4(acc[0], acc[1], acc[2], acc[3]);
        *reinterpret_cast<float4*>(out + rowoff + lane * 8 + 4) =
            make_float4(acc[4], acc[5], acc[6], acc[7]);
    }
}

// ---- fallback: f32 kernel (used if ws too small) ----
__global__ __launch_bounds__(256) void wayfinder_attn_f32(
    const float* __restrict__ q, const float* __restrict__ k,
    const float* __restrict__ v, const float* __restrict__ eb,
    const int* __restrict__ nidx, const int* __restrict__ etyp,
    float* __restrict__ out)
{
    const int wave = threadIdx.x >> 6;
    const int lane = threadIdx.x & 63;
    const int flat = (blockIdx.x << 2) + wave;
    const int h    = flat >> 11;
    const int t    = flat & (T - 1);
    const int grp  = lane >> 4;
    const int sub  = lane & 15;

    __shared__ int    sidx[4][64];
    __shared__ float  ssc [4][64];
    __shared__ float2 swv [4][64];

    const long long rowoff = (long long)flat * DH;
    const long long noff = (long long)flat * D + lane;
    const int  idx = nidx[noff];
    const int  et  = etyp[noff];
    const int  s   = min(max(idx, 0), T - 1);
    const bool msk = (idx >= 0) && (idx <= t);
    const float4 ebv  = *reinterpret_cast<const float4*>(eb);
    const float  bias = (et == 1) ? ebv.x : (et == 2) ? ebv.y :
                        (et == 3) ? ebv.z : (et == 4) ? ebv.w : 0.0f;
    sidx[wave][lane] = s;
    const float4 qf = *reinterpret_cast<const float4*>(q + rowoff + sub * 4);
    __syncthreads();

    const float* khead = k + (long long)h * T * DH;
    #pragma unroll
    for (int i = 0; i < 16; ++i) {
        const int n  = i * 4 + grp;
        const int sn = sidx[wave][n];
        const float4 kf = *reinterpret_cast<const float4*>(khead + sn * DH + sub * 4);
        float p = qf.x * kf.x + qf.y * kf.y + qf.z * kf.z + qf.w * kf.w;
        p += __shfl_xor(p, 1);
        p += __shfl_xor(p, 2);
        p += __shfl_xor(p, 4);
        p += __shfl_xor(p, 8);
        if (sub == 0) ssc[wave][n] = p;
    }
    __syncthreads();

    const float sc     = ssc[wave][lane];
    const float masked = msk ? (sc * 0.125f + bias) : -1e30f;
    float mx = masked;
    #pragma unroll
    for (int off = 32; off > 0; off >>= 1) mx = fmaxf(mx, __shfl_xor(mx, off));
    const float e = msk ? __expf(masked - mx) : 0.0f;
    float sum = e;
    #pragma unroll
    for (int off = 32; off > 0; off >>= 1) sum += __shfl_xor(sum, off);
    const float w = e / fmaxf(sum, 1e-9f);
    swv[wave][lane] = make_float2(w, __int_as_float(s));
    __syncthreads();

    const float* vhead = v + (long long)h * T * DH;
    float4 acc = make_float4(0.f, 0.f, 0.f, 0.f);
    #pragma unroll
    for (int i = 0; i < 16; ++i) {
        const int    n  = i * 4 + grp;
        const float2 ws = swv[wave][n];
        const int    sn = __float_as_int(ws.y);
        const float4 vf = *reinterpret_cast<const float4*>(vhead + sn * DH + sub * 4);
        acc.x += ws.x * vf.x; acc.y += ws.x * vf.y;
        acc.z += ws.x * vf.z; acc.w += ws.x * vf.w;
    }
    #pragma unroll
    for (int off = 16; off <= 32; off <<= 1) {
        acc.x += __shfl_xor(acc.x, off); acc.y += __shfl_xor(acc.y, off);
        acc.z += __shfl_xor(acc.z, off); acc.w += __shfl_xor(acc.w, off);
    }
    if (lane < 16)
        *reinterpret_cast<float4*>(out + rowoff + sub * 4) = acc;
}

extern "C" void kernel_launch(void* const* d_in, const int* in_sizes, int n_in,
                              void* d_out, int out_size, void* d_ws, size_t ws_size,
                              hipStream_t stream) {
    const float* q    = (const float*)d_in[0];
    const float* k    = (const float*)d_in[1];
    const float* v    = (const float*)d_in[2];
    const float* eb   = (const float*)d_in[3];
    const int*   nidx = (const int*)d_in[4];
    const int*   etyp = (const int*)d_in[5];
    float* out = (float*)d_out;

    const size_t need = (size_t)2 * NKV * sizeof(__half);   // 4 MB
    if (ws_size >= need) {
        __half* kh = (__half*)d_ws;
        __half* vh = kh + NKV;
        dim3 cgrid(NKV / (256 * 8), 2);
        hipLaunchKernelGGL(cvt_f32_f16, cgrid, dim3(256), 0, stream, k, v, kh, vh);
        hipLaunchKernelGGL(wayfinder_attn_f16, dim3(H * T / 4), dim3(256), 0, stream,
                           q, kh, vh, eb, nidx, etyp, out);
    } else {
        hipLaunchKernelGGL(wayfinder_attn_f32, dim3(H * T / 4), dim3(256), 0, stream,
                           q, k, v, eb, nidx, etyp, out);
    }
}

// Round 5
// 26.379 us; speedup vs baseline: 2.1716x; 1.0716x over previous
//
#include <hip/hip_runtime.h>
#include <hip/hip_fp16.h>

constexpr int H  = 8;
constexpr int T  = 2048;
constexpr int DH = 64;
constexpr int D  = 64;
constexpr int NKV = H * T * DH;   // 1M elements per tensor

// ---- prepass: f32 -> f16 for k and v (into workspace) ----
__global__ __launch_bounds__(256) void cvt_f32_f16(
    const float* __restrict__ k, const float* __restrict__ v,
    __half* __restrict__ kh, __half* __restrict__ vh)
{
    const int i = (blockIdx.x * 256 + threadIdx.x) * 8;
    const float* src = (blockIdx.y == 0) ? k : v;
    __half*      dst = (blockIdx.y == 0) ? kh : vh;
    const float4 a = *reinterpret_cast<const float4*>(src + i);
    const float4 b = *reinterpret_cast<const float4*>(src + i + 4);
    __half2 hh[4];
    hh[0] = __float22half2_rn(make_float2(a.x, a.y));
    hh[1] = __float22half2_rn(make_float2(a.z, a.w));
    hh[2] = __float22half2_rn(make_float2(b.x, b.y));
    hh[3] = __float22half2_rn(make_float2(b.z, b.w));
    *reinterpret_cast<float4*>(dst + i) = *reinterpret_cast<const float4*>(hh);
}

// ---- main: fp16 gathers, no LDS/barriers, XCD-head affinity ----
// grp = lane>>3 (row-group), sub = lane&7 (8-channel slice).
// Register entry i <-> neighbor n = i*8 + grp. Metadata is loaded DIRECTLY
// in this layout (tiny broadcast loads) so gather addresses form with no
// shfl dependency. Blocks are swizzled so XCD i serves head i exclusively:
// that head's k+v (512 KB fp16) stays resident in the XCD's 4 MB L2.
__global__ __launch_bounds__(256) void wayfinder_attn_f16(
    const float* __restrict__ q,
    const __half* __restrict__ kh,
    const __half* __restrict__ vh,
    const float* __restrict__ eb,
    const int*   __restrict__ nidx,
    const int*   __restrict__ etyp,
    float* __restrict__ out)
{
    const int wave = threadIdx.x >> 6;
    const int lane = threadIdx.x & 63;
    // XCD-head affinity: 4096 blocks, assume round-robin bid->XCD (bid&7).
    // work = (bid&7)*512 + bid>>3  => head(work) == bid&7. Bijective.
    const int bid  = blockIdx.x;
    const int work = ((bid & 7) << 9) | (bid >> 3);
    const int flat = (work << 2) + wave;         // h*T + t
    const int h    = flat >> 11;
    const int t    = flat & (T - 1);
    const int grp  = lane >> 3;
    const int sub  = lane & 7;

    const long long rowoff = (long long)flat * DH;
    const int*      nrow   = nidx + (long long)flat * D;
    const int*      erow   = etyp + (long long)flat * D;

    // metadata directly in gather layout: entry i = neighbor i*8+grp.
    // 8 lanes broadcast each value; 1 line per load; all issue immediately.
    int idx_i[8], et_i[8];
    #pragma unroll
    for (int i = 0; i < 8; ++i) idx_i[i] = nrow[i * 8 + grp];
    #pragma unroll
    for (int i = 0; i < 8; ++i) et_i[i]  = erow[i * 8 + grp];

    // q fragment: channels sub*8 .. sub*8+7 (broadcast across grp)
    const float4 q0 = *reinterpret_cast<const float4*>(q + rowoff + sub * 8);
    const float4 q1 = *reinterpret_cast<const float4*>(q + rowoff + sub * 8 + 4);

    const __half* khead = kh + (long long)h * T * DH;
    const __half* vhead = vh + (long long)h * T * DH;

    // gathers: one dwordx4 = full fp16 row per 8-lane group
    float4 kf[8], vf[8];
    #pragma unroll
    for (int i = 0; i < 8; ++i) {
        const int s = min(max(idx_i[i], 0), T - 1);
        const long long ro = (long long)s * DH + sub * 8;
        kf[i] = *reinterpret_cast<const float4*>(khead + ro);
        vf[i] = *reinterpret_cast<const float4*>(vhead + ro);
    }

    const float4 ebv = *reinterpret_cast<const float4*>(eb);

    // QK: per-lane 8-channel partial, full dot via 3 intra-group shfl levels
    float sc[8];
    #pragma unroll
    for (int i = 0; i < 8; ++i) {
        const __half2* kp = reinterpret_cast<const __half2*>(&kf[i]);
        const float2 f0 = __half22float2(kp[0]);
        const float2 f1 = __half22float2(kp[1]);
        const float2 f2 = __half22float2(kp[2]);
        const float2 f3 = __half22float2(kp[3]);
        float p = q0.x * f0.x + q0.y * f0.y + q0.z * f1.x + q0.w * f1.y
                + q1.x * f2.x + q1.y * f2.y + q1.z * f3.x + q1.w * f3.y;
        p += __shfl_xor(p, 1);
        p += __shfl_xor(p, 2);
        p += __shfl_xor(p, 4);
        sc[i] = p;
    }

    // masked softmax: local over 8 entries, then 3 cross-group shfl levels
    bool  msk[8];
    float masked[8];
    float mx = -1e30f;
    #pragma unroll
    for (int i = 0; i < 8; ++i) {
        const int et = et_i[i];
        const float bias = (et == 1) ? ebv.x : (et == 2) ? ebv.y :
                           (et == 3) ? ebv.z : (et == 4) ? ebv.w : 0.0f;
        msk[i]    = (idx_i[i] >= 0) && (idx_i[i] <= t);
        masked[i] = msk[i] ? (sc[i] * 0.125f + bias) : -1e30f;
        mx = fmaxf(mx, masked[i]);
    }
    mx = fmaxf(mx, __shfl_xor(mx, 8));
    mx = fmaxf(mx, __shfl_xor(mx, 16));
    mx = fmaxf(mx, __shfl_xor(mx, 32));

    float e[8];
    float sum = 0.0f;
    #pragma unroll
    for (int i = 0; i < 8; ++i) {
        e[i] = msk[i] ? __expf(masked[i] - mx) : 0.0f;
        sum += e[i];
    }
    sum += __shfl_xor(sum, 8);
    sum += __shfl_xor(sum, 16);
    sum += __shfl_xor(sum, 32);
    const float rden = 1.0f / fmaxf(sum, 1e-9f);

    // PV from registers (weights already in this layout)
    float acc[8] = {0.f, 0.f, 0.f, 0.f, 0.f, 0.f, 0.f, 0.f};
    #pragma unroll
    for (int i = 0; i < 8; ++i) {
        const float w = e[i] * rden;
        const __half2* vp = reinterpret_cast<const __half2*>(&vf[i]);
        const float2 f0 = __half22float2(vp[0]);
        const float2 f1 = __half22float2(vp[1]);
        const float2 f2 = __half22float2(vp[2]);
        const float2 f3 = __half22float2(vp[3]);
        acc[0] += w * f0.x;  acc[1] += w * f0.y;
        acc[2] += w * f1.x;  acc[3] += w * f1.y;
        acc[4] += w * f2.x;  acc[5] += w * f2.y;
        acc[6] += w * f3.x;  acc[7] += w * f3.y;
    }
    #pragma unroll
    for (int c = 0; c < 8; ++c) {
        acc[c] += __shfl_xor(acc[c], 8);
        acc[c] += __shfl_xor(acc[c], 16);
        acc[c] += __shfl_xor(acc[c], 32);
    }
    // 16 lanes store one float4 each: lane<8 -> low half, lane 8..15 -> high
    if (lane < 16) {
        const int s8   = (lane & 7) * 8;
        const int half = (lane >> 3) * 4;
        const float4 o = (half == 0)
            ? make_float4(acc[0], acc[1], acc[2], acc[3])
            : make_float4(acc[4], acc[5], acc[6], acc[7]);
        *reinterpret_cast<float4*>(out + rowoff + s8 + half) = o;
    }
}

// ---- fallback: f32 kernel (used if ws too small) ----
__global__ __launch_bounds__(256) void wayfinder_attn_f32(
    const float* __restrict__ q, const float* __restrict__ k,
    const float* __restrict__ v, const float* __restrict__ eb,
    const int* __restrict__ nidx, const int* __restrict__ etyp,
    float* __restrict__ out)
{
    const int wave = threadIdx.x >> 6;
    const int lane = threadIdx.x & 63;
    const int flat = (blockIdx.x << 2) + wave;
    const int h    = flat >> 11;
    const int t    = flat & (T - 1);
    const int grp  = lane >> 4;
    const int sub  = lane & 15;

    __shared__ int    sidx[4][64];
    __shared__ float  ssc [4][64];
    __shared__ float2 swv [4][64];

    const long long rowoff = (long long)flat * DH;
    const long long noff = (long long)flat * D + lane;
    const int  idx = nidx[noff];
    const int  et  = etyp[noff];
    const int  s   = min(max(idx, 0), T - 1);
    const bool msk = (idx >= 0) && (idx <= t);
    const float4 ebv  = *reinterpret_cast<const float4*>(eb);
    const float  bias = (et == 1) ? ebv.x : (et == 2) ? ebv.y :
                        (et == 3) ? ebv.z : (et == 4) ? ebv.w : 0.0f;
    sidx[wave][lane] = s;
    const float4 qf = *reinterpret_cast<const float4*>(q + rowoff + sub * 4);
    __syncthreads();

    const float* khead = k + (long long)h * T * DH;
    #pragma unroll
    for (int i = 0; i < 16; ++i) {
        const int n  = i * 4 + grp;
        const int sn = sidx[wave][n];
        const float4 kf = *reinterpret_cast<const float4*>(khead + sn * DH + sub * 4);
        float p = qf.x * kf.x + qf.y * kf.y + qf.z * kf.z + qf.w * kf.w;
        p += __shfl_xor(p, 1);
        p += __shfl_xor(p, 2);
        p += __shfl_xor(p, 4);
        p += __shfl_xor(p, 8);
        if (sub == 0) ssc[wave][n] = p;
    }
    __syncthreads();

    const float sc     = ssc[wave][lane];
    const float masked = msk ? (sc * 0.125f + bias) : -1e30f;
    float mx = masked;
    #pragma unroll
    for (int off = 32; off > 0; off >>= 1) mx = fmaxf(mx, __shfl_xor(mx, off));
    const float e = msk ? __expf(masked - mx) : 0.0f;
    float sum = e;
    #pragma unroll
    for (int off = 32; off > 0; off >>= 1) sum += __shfl_xor(sum, off);
    const float w = e / fmaxf(sum, 1e-9f);
    swv[wave][lane] = make_float2(w, __int_as_float(s));
    __syncthreads();

    const float* vhead = v + (long long)h * T * DH;
    float4 acc = make_float4(0.f, 0.f, 0.f, 0.f);
    #pragma unroll
    for (int i = 0; i < 16; ++i) {
        const int    n  = i * 4 + grp;
        const float2 ws = swv[wave][n];
        const int    sn = __float_as_int(ws.y);
        const float4 vf = *reinterpret_cast<const float4*>(vhead + sn * DH + sub * 4);
        acc.x += ws.x * vf.x; acc.y += ws.x * vf.y;
        acc.z += ws.x * vf.z; acc.w += ws.x * vf.w;
    }
    #pragma unroll
    for (int off = 16; off <= 32; off <<= 1) {
        acc.x += __shfl_xor(acc.x, off); acc.y += __shfl_xor(acc.y, off);
        acc.z += __shfl_xor(acc.z, off); acc.w += __shfl_xor(acc.w, off);
    }
    if (lane < 16)
        *reinterpret_cast<float4*>(out + rowoff + sub * 4) = acc;
}

extern "C" void kernel_launch(void* const* d_in, const int* in_sizes, int n_in,
                              void* d_out, int out_size, void* d_ws, size_t ws_size,
                              hipStream_t stream) {
    const float* q    = (const float*)d_in[0];
    const float* k    = (const float*)d_in[1];
    const float* v    = (const float*)d_in[2];
    const float* eb   = (const float*)d_in[3];
    const int*   nidx = (const int*)d_in[4];
    const int*   etyp = (const int*)d_in[5];
    float* out = (float*)d_out;

    const size_t need = (size_t)2 * NKV * sizeof(__half);   // 4 MB
    if (ws_size >= need) {
        __half* kh = (__half*)d_ws;
        __half* vh = kh + NKV;
        dim3 cgrid(NKV / (256 * 8), 2);
        hipLaunchKernelGGL(cvt_f32_f16, cgrid, dim3(256), 0, stream, k, v, kh, vh);
        hipLaunchKernelGGL(wayfinder_attn_f16, dim3(H * T / 4), dim3(256), 0, stream,
                           q, kh, vh, eb, nidx, etyp, out);
    } else {
        hipLaunchKernelGGL(wayfinder_attn_f32, dim3(H * T / 4), dim3(256), 0, stream,
                           q, k, v, eb, nidx, etyp, out);
    }
}